// Round 3
// baseline (1337.283 us; speedup 1.0000x reference)
//
#include <hip/hip_runtime.h>
#include <math.h>

#define NHEADS 16
#define HD 64
#define MMEM 16384
#define NQ 1024   // B*S per head
#define SEQ 512
#define EPS 1e-8f

// ---------------------------------------------------------------------------
// Kernel 1: reciprocal L2 norm of each key-memory row: knr[h*M+m] = 1/max(||k||,eps)
// 16 lanes cooperate per row (coalesced float4 reads), shfl-xor reduce.
// ---------------------------------------------------------------------------
__global__ void knorm_kernel(const float* __restrict__ kmem,
                             float* __restrict__ knr) {
    int gid = blockIdx.x * 256 + threadIdx.x;
    int mem = gid >> 4;   // 0 .. NHEADS*MMEM-1
    int d4  = gid & 15;
    float4 kv = reinterpret_cast<const float4*>(kmem)[(size_t)mem * 16 + d4];
    float ss = kv.x * kv.x + kv.y * kv.y + kv.z * kv.z + kv.w * kv.w;
    ss += __shfl_xor(ss, 1);
    ss += __shfl_xor(ss, 2);
    ss += __shfl_xor(ss, 4);
    ss += __shfl_xor(ss, 8);
    if (d4 == 0) knr[mem] = 1.0f / fmaxf(sqrtf(ss), EPS);
}

// ---------------------------------------------------------------------------
// Kernel 2: similarity scan + per-lane running top-8.
// One wave per block (__launch_bounds__(64,4) -> 128-VGPR cap, 4 waves/SIMD).
// Wave = 64 queries (one per lane). ALL loops touching q[] are fully unrolled
// so every index is a compile-time constant -> SROA keeps q[] in VGPRs
// (rule: runtime-indexed arrays go to scratch). k-row addresses are
// wave-uniform (one 64B line broadcast, L1/L2-resident).
// ---------------------------------------------------------------------------
__global__ __launch_bounds__(64, 4)
void scan_kernel(const float* __restrict__ query,
                 const float* __restrict__ kmem,
                 const float* __restrict__ knr,
                 float* __restrict__ pscore,
                 int* __restrict__ pidx,
                 int P, int CH) {
    const int lane = threadIdx.x & 63;
    int bid = blockIdx.x;
    const int p  = bid % P;  bid /= P;
    const int qb = bid & 15; bid >>= 4;
    const int h  = bid;
    const int n  = qb * 64 + lane;       // query index within head
    const int b  = n >> 9;
    const int s  = n & 511;

    // load query, compute norm, fold 1/(max(norm,eps)*sqrt(64)) into q
    const float4* qp = reinterpret_cast<const float4*>(
        query + (((size_t)b * NHEADS + h) * SEQ + s) * HD);
    float q[HD];
    float ss = 0.0f;
#pragma unroll
    for (int i = 0; i < 16; ++i) {
        float4 v = qp[i];
        q[4*i+0] = v.x; q[4*i+1] = v.y; q[4*i+2] = v.z; q[4*i+3] = v.w;
        ss += v.x * v.x + v.y * v.y + v.z * v.z + v.w * v.w;
    }
    const float rq = 1.0f / (fmaxf(sqrtf(ss), EPS) * 8.0f);
#pragma unroll
    for (int i = 0; i < HD; ++i) q[i] *= rq;   // fully unrolled -> SROA

    float tv[8]; int ti[8];
#pragma unroll
    for (int j = 0; j < 8; ++j) { tv[j] = -INFINITY; ti[j] = 0; }

    const int m0 = p * CH;
    const float4* kp = reinterpret_cast<const float4*>(
        kmem + ((size_t)h * MMEM + m0) * HD);
    const float* knrp = knr + h * MMEM + m0;

    for (int mm = 0; mm < CH; ++mm) {
        float d0 = 0.f, d1 = 0.f, d2 = 0.f, d3 = 0.f;
#pragma unroll
        for (int i = 0; i < 16; ++i) {
            float4 kv = kp[(size_t)mm * 16 + i];   // wave-uniform -> broadcast
            d0 = fmaf(q[4*i+0], kv.x, d0);
            d1 = fmaf(q[4*i+1], kv.y, d1);
            d2 = fmaf(q[4*i+2], kv.z, d2);
            d3 = fmaf(q[4*i+3], kv.w, d3);
        }
        const float sim = ((d0 + d1) + (d2 + d3)) * knrp[mm];
        if (sim > tv[7]) {                 // strict > keeps lower index on ties
            tv[7] = sim; ti[7] = m0 + mm;
#pragma unroll
            for (int j = 7; j > 0; --j) {
                if (tv[j] > tv[j-1]) {
                    float tf = tv[j]; tv[j] = tv[j-1]; tv[j-1] = tf;
                    int   tu = ti[j]; ti[j] = ti[j-1]; ti[j-1] = tu;
                }
            }
        }
    }

    const size_t base = (((size_t)h * NQ + n) * P + p) * 8;
#pragma unroll
    for (int j = 0; j < 8; ++j) { pscore[base+j] = tv[j]; pidx[base+j] = ti[j]; }
}

// ---------------------------------------------------------------------------
// Kernel 3: merge P partial top-8 lists per query (ascending-partition order
// preserves lower-index-first ties), gather top-8 value rows, weighted sum,
// sigmoid-gate blend with `outputs`.
// ---------------------------------------------------------------------------
__global__ void merge_kernel(const float* __restrict__ pscore,
                             const int* __restrict__ pidx,
                             const float* __restrict__ vmem,
                             const float* __restrict__ outputs,
                             const float* __restrict__ gate,
                             float* __restrict__ out, int P) {
    const int t = blockIdx.x * 256 + threadIdx.x;   // 0 .. NHEADS*NQ-1
    const int h = t >> 10;
    const int n = t & 1023;
    const int b = n >> 9;
    const int s = n & 511;

    float tv[8]; int ti[8];
    const size_t base = ((size_t)h * NQ + n) * P * 8;
#pragma unroll
    for (int j = 0; j < 8; ++j) { tv[j] = pscore[base+j]; ti[j] = pidx[base+j]; }
    const int total = P * 8;
    for (int c = 8; c < total; ++c) {
        const float v = pscore[base + c];
        if (v > tv[7]) {
            tv[7] = v; ti[7] = pidx[base + c];
#pragma unroll
            for (int j = 7; j > 0; --j) {
                if (tv[j] > tv[j-1]) {
                    float tf = tv[j]; tv[j] = tv[j-1]; tv[j-1] = tf;
                    int   tu = ti[j]; ti[j] = ti[j-1]; ti[j-1] = tu;
                }
            }
        }
    }

    float4 acc[16];
#pragma unroll
    for (int i = 0; i < 16; ++i) acc[i] = make_float4(0.f, 0.f, 0.f, 0.f);
#pragma unroll
    for (int j = 0; j < 8; ++j) {
        const float4* vp = reinterpret_cast<const float4*>(
            vmem + ((size_t)h * MMEM + ti[j]) * HD);
        const float sc = tv[j];
#pragma unroll
        for (int i = 0; i < 16; ++i) {
            float4 v = vp[i];
            acc[i].x = fmaf(sc, v.x, acc[i].x);
            acc[i].y = fmaf(sc, v.y, acc[i].y);
            acc[i].z = fmaf(sc, v.z, acc[i].z);
            acc[i].w = fmaf(sc, v.w, acc[i].w);
        }
    }

    const float g  = 1.0f / (1.0f + expf(-gate[h]));
    const float og = 1.0f - g;
    const size_t off = (((size_t)b * NHEADS + h) * SEQ + s) * HD;
    const float4* op = reinterpret_cast<const float4*>(outputs + off);
    float4* dst = reinterpret_cast<float4*>(out + off);
#pragma unroll
    for (int i = 0; i < 16; ++i) {
        float4 o = op[i];
        float4 r;
        r.x = g * acc[i].x + og * o.x;
        r.y = g * acc[i].y + og * o.y;
        r.z = g * acc[i].z + og * o.z;
        r.w = g * acc[i].w + og * o.w;
        dst[i] = r;
    }
}

// ---------------------------------------------------------------------------
extern "C" void kernel_launch(void* const* d_in, const int* in_sizes, int n_in,
                              void* d_out, int out_size, void* d_ws, size_t ws_size,
                              hipStream_t stream) {
    // setup_inputs order: inputs, query, key, value, outputs, gate,
    //                     key_memories, value_memories
    const float* query   = (const float*)d_in[1];
    const float* outputs = (const float*)d_in[4];
    const float* gate    = (const float*)d_in[5];
    const float* kmem    = (const float*)d_in[6];
    const float* vmem    = (const float*)d_in[7];
    float* out = (float*)d_out;

    // workspace: knr (1 MB) + pscore/pidx partials (P MB total, 64B/query/part)
    int P = 16;
    while (P > 4 &&
           (size_t)NHEADS * MMEM * 4 + (size_t)NHEADS * NQ * (size_t)P * 64 > ws_size)
        P >>= 1;
    const int CH = MMEM / P;

    float* knr    = (float*)d_ws;
    float* pscore = knr + (size_t)NHEADS * MMEM;
    int*   pidx   = (int*)(pscore + (size_t)NHEADS * NQ * (size_t)P * 8);

    knorm_kernel<<<(NHEADS * MMEM * 16) / 256, 256, 0, stream>>>(kmem, knr);
    scan_kernel<<<NHEADS * 16 * P, 64, 0, stream>>>(
        query, kmem, knr, pscore, pidx, P, CH);
    merge_kernel<<<(NHEADS * NQ) / 256, 256, 0, stream>>>(
        pscore, pidx, vmem, outputs, gate, out, P);
}

// Round 4
// 852.409 us; speedup vs baseline: 1.5688x; 1.5688x over previous
//
#include <hip/hip_runtime.h>
#include <math.h>

#define NHEADS 16
#define HD 64
#define MMEM 16384
#define NQ 1024   // B*S per head
#define SEQ 512
#define EPS 1e-8f

typedef short bf16x8 __attribute__((ext_vector_type(8)));
typedef float f32x16 __attribute__((ext_vector_type(16)));

typedef const __attribute__((address_space(1))) unsigned int* gas_u32p;
typedef __attribute__((address_space(3))) unsigned int* las_u32p;

__device__ inline unsigned short f2bf(float f) {
    unsigned int u = __builtin_bit_cast(unsigned int, f);
    unsigned int r = (u + 0x7FFFu + ((u >> 16) & 1u)) >> 16;  // RNE
    return (unsigned short)r;
}

// ---------------------------------------------------------------------------
// Kernel 1: reciprocal L2 norm per key-memory row.
// ---------------------------------------------------------------------------
__global__ void knorm_kernel(const float* __restrict__ kmem,
                             float* __restrict__ knr) {
    int gid = blockIdx.x * 256 + threadIdx.x;
    int mem = gid >> 4;
    int d4  = gid & 15;
    float4 kv = reinterpret_cast<const float4*>(kmem)[(size_t)mem * 16 + d4];
    float ss = kv.x * kv.x + kv.y * kv.y + kv.z * kv.z + kv.w * kv.w;
    ss += __shfl_xor(ss, 1);
    ss += __shfl_xor(ss, 2);
    ss += __shfl_xor(ss, 4);
    ss += __shfl_xor(ss, 8);
    if (d4 == 0) knr[mem] = 1.0f / fmaxf(sqrtf(ss), EPS);
}

// ---------------------------------------------------------------------------
// Kernel 2: normalized bf16 keys in MFMA-A-fragment tile order.
// Tile = 32 mems x 64 d. Byte layout: (((h*512+t)*4+ks)*64+lane)*16 + j*2
// holds kmem[h][t*32+(lane&31)][ks*16+(lane>>5)*8+j] * knr (bf16).
// gid enumerates (h,t,ks,lane) exactly in output order -> out[gid*8..+7].
// ---------------------------------------------------------------------------
__global__ __launch_bounds__(256)
void kprep_kernel(const float* __restrict__ kmem,
                  const float* __restrict__ knr,
                  unsigned short* __restrict__ kbf) {
    int gid = blockIdx.x * 256 + threadIdx.x;
    int lane = gid & 63;
    int ks   = (gid >> 6) & 3;
    int t    = (gid >> 8) & 511;
    int h    = gid >> 17;
    int row  = t * 32 + (lane & 31);
    int d0   = ks * 16 + ((lane >> 5) << 3);
    const float* src = kmem + (((size_t)h * MMEM + row) << 6) + d0;
    float sc = knr[h * MMEM + row];
    float4 v0 = *(const float4*)(src);
    float4 v1 = *(const float4*)(src + 4);
    uint4 o;
    o.x = (unsigned)f2bf(v0.x * sc) | ((unsigned)f2bf(v0.y * sc) << 16);
    o.y = (unsigned)f2bf(v0.z * sc) | ((unsigned)f2bf(v0.w * sc) << 16);
    o.z = (unsigned)f2bf(v1.x * sc) | ((unsigned)f2bf(v1.y * sc) << 16);
    o.w = (unsigned)f2bf(v1.z * sc) | ((unsigned)f2bf(v1.w * sc) << 16);
    *(uint4*)(kbf + (size_t)gid * 8) = o;
}

// ---------------------------------------------------------------------------
// Kernel 3: MFMA candidate scan. Grid (h=16, qgb=4, p=8) = 512 blocks x 256.
// Wave: 64 queries (2 col-groups of 32) x 2048-mem partition, 64 tiles.
// D = mfma_32x32x16(K_tile, Q): col=lane&31 (query), 16 rows/lane (mems).
// Per-lane running top-8 per col-group; 16 candidates per (query,partition).
// ---------------------------------------------------------------------------
#define EPILOG(ACC, TV, TI, MB) do {                                          \
    float _m = fmaxf(fmaxf(fmaxf(ACC[0],ACC[1]),fmaxf(ACC[2],ACC[3])),        \
                     fmaxf(fmaxf(ACC[4],ACC[5]),fmaxf(ACC[6],ACC[7])));       \
    _m = fmaxf(_m, fmaxf(fmaxf(fmaxf(ACC[8],ACC[9]),fmaxf(ACC[10],ACC[11])), \
                         fmaxf(fmaxf(ACC[12],ACC[13]),fmaxf(ACC[14],ACC[15]))));\
    if (_m > TV[7]) {                                                         \
        _Pragma("unroll")                                                     \
        for (int _r = 0; _r < 16; ++_r) {                                     \
            float _v = ACC[_r];                                               \
            if (_v > TV[7]) {                                                 \
                TV[7] = _v; TI[7] = (MB) + (_r & 3) + 8 * (_r >> 2);          \
                _Pragma("unroll")                                             \
                for (int _j = 7; _j > 0; --_j) {                              \
                    if (TV[_j] > TV[_j-1]) {                                  \
                        float _tf = TV[_j]; TV[_j] = TV[_j-1]; TV[_j-1] = _tf;\
                        int _tu = TI[_j]; TI[_j] = TI[_j-1]; TI[_j-1] = _tu;  \
                    } } } } }                                                 \
} while (0)

__device__ inline bf16x8 pack8(const float* p) {
    float4 a = *(const float4*)p;
    float4 b = *(const float4*)(p + 4);
    bf16x8 f;
    f[0] = (short)f2bf(a.x); f[1] = (short)f2bf(a.y);
    f[2] = (short)f2bf(a.z); f[3] = (short)f2bf(a.w);
    f[4] = (short)f2bf(b.x); f[5] = (short)f2bf(b.y);
    f[6] = (short)f2bf(b.z); f[7] = (short)f2bf(b.w);
    return f;
}

__global__ __launch_bounds__(256, 2)
void scan_mfma_kernel(const float* __restrict__ query,
                      const unsigned short* __restrict__ kbf,
                      int* __restrict__ pcand) {
    __shared__ __align__(16) unsigned char lds[2][4096];
    const int tid  = threadIdx.x;
    const int lane = tid & 63;
    const int wid  = tid >> 6;
    int bid = blockIdx.x;
    const int p   = bid & 7;  bid >>= 3;
    const int qgb = bid & 3;  bid >>= 2;
    const int h   = bid;

    const int col = lane & 31;
    const int hi  = lane >> 5;
    const int n0  = qgb * 256 + wid * 64 + col;   // query col-group A
    const int n1  = n0 + 32;                      // col-group B

    // B fragments: col=lane&31 (query), k = ks*16 + hi*8 + j  (raw q; per-query
    // scale does not affect that query's ranking)
    bf16x8 qfA[4], qfB[4];
    {
        const int b0 = n0 >> 9, s0 = n0 & 511;
        const int b1 = n1 >> 9, s1 = n1 & 511;
        const float* qp0 = query + ((((size_t)b0 * NHEADS + h) * SEQ + s0) << 6);
        const float* qp1 = query + ((((size_t)b1 * NHEADS + h) * SEQ + s1) << 6);
#pragma unroll
        for (int ks = 0; ks < 4; ++ks) {
            const int d0 = ks * 16 + hi * 8;
            qfA[ks] = pack8(qp0 + d0);
            qfB[ks] = pack8(qp1 + d0);
        }
    }

    float tvA[8], tvB[8]; int tiA[8], tiB[8];
#pragma unroll
    for (int j = 0; j < 8; ++j) {
        tvA[j] = -1e30f; tvB[j] = -1e30f; tiA[j] = 0; tiB[j] = 0;
    }

    const unsigned char* gbase = (const unsigned char*)kbf;
    const size_t tile0 = ((size_t)h * 512 + (size_t)p * 64) * 4096;

    // prologue: stage tile 0
    __builtin_amdgcn_global_load_lds(
        (gas_u32p)(const void*)(gbase + tile0 + (size_t)tid * 16),
        (las_u32p)(void*)(&lds[0][wid * 1024]), 16, 0, 0);
    __syncthreads();

#pragma unroll 1
    for (int t = 0; t < 64; ++t) {
        const int cur = t & 1, nxt = cur ^ 1;
        if (t < 63) {
            __builtin_amdgcn_global_load_lds(
                (gas_u32p)(const void*)(gbase + tile0 + (size_t)(t + 1) * 4096 + (size_t)tid * 16),
                (las_u32p)(void*)(&lds[nxt][wid * 1024]), 16, 0, 0);
        }
        bf16x8 af0 = *(const bf16x8*)(&lds[cur][0 * 1024 + lane * 16]);
        bf16x8 af1 = *(const bf16x8*)(&lds[cur][1 * 1024 + lane * 16]);
        bf16x8 af2 = *(const bf16x8*)(&lds[cur][2 * 1024 + lane * 16]);
        bf16x8 af3 = *(const bf16x8*)(&lds[cur][3 * 1024 + lane * 16]);

        f32x16 accA = {0,0,0,0,0,0,0,0,0,0,0,0,0,0,0,0};
        f32x16 accB = {0,0,0,0,0,0,0,0,0,0,0,0,0,0,0,0};
        accA = __builtin_amdgcn_mfma_f32_32x32x16_bf16(af0, qfA[0], accA, 0, 0, 0);
        accB = __builtin_amdgcn_mfma_f32_32x32x16_bf16(af0, qfB[0], accB, 0, 0, 0);
        accA = __builtin_amdgcn_mfma_f32_32x32x16_bf16(af1, qfA[1], accA, 0, 0, 0);
        accB = __builtin_amdgcn_mfma_f32_32x32x16_bf16(af1, qfB[1], accB, 0, 0, 0);
        accA = __builtin_amdgcn_mfma_f32_32x32x16_bf16(af2, qfA[2], accA, 0, 0, 0);
        accB = __builtin_amdgcn_mfma_f32_32x32x16_bf16(af2, qfB[2], accB, 0, 0, 0);
        accA = __builtin_amdgcn_mfma_f32_32x32x16_bf16(af3, qfA[3], accA, 0, 0, 0);
        accB = __builtin_amdgcn_mfma_f32_32x32x16_bf16(af3, qfB[3], accB, 0, 0, 0);

        const int mbase = p * 2048 + t * 32 + 4 * hi;
        EPILOG(accA, tvA, tiA, mbase);
        EPILOG(accB, tvB, tiB, mbase);
        __syncthreads();
    }

    const size_t baseA = (((size_t)h * NQ + n0) * 8 + p) * 16 + hi * 8;
    const size_t baseB = (((size_t)h * NQ + n1) * 8 + p) * 16 + hi * 8;
#pragma unroll
    for (int j = 0; j < 8; ++j) {
        pcand[baseA + j] = tiA[j];
        pcand[baseB + j] = tiB[j];
    }
}

// ---------------------------------------------------------------------------
// Kernel 4: exact fp32 rescore of 16 candidates per (query, partition);
// per-partition top-8 with (score desc, idx asc) tie rule.
// ---------------------------------------------------------------------------
#define KROW(I, Q) kv = kp[I]; \
    a0 = fmaf(Q.x, kv.x, a0); a1 = fmaf(Q.y, kv.y, a1); \
    a2 = fmaf(Q.z, kv.z, a2); a3 = fmaf(Q.w, kv.w, a3);
#define SS(Q) (Q.x*Q.x + Q.y*Q.y + Q.z*Q.z + Q.w*Q.w)

__global__ __launch_bounds__(256, 4)
void rescore_kernel(const float* __restrict__ query,
                    const float* __restrict__ kmem,
                    const float* __restrict__ knr,
                    const int* __restrict__ pcand,
                    float* __restrict__ pscore,
                    int* __restrict__ pidx) {
    int gid = blockIdx.x * 256 + threadIdx.x;  // (h, q, p)
    int p = gid & 7;
    int n = (gid >> 3) & 1023;
    int h = gid >> 13;
    int b = n >> 9, s = n & 511;
    const float4* qv = (const float4*)(query + ((((size_t)b * NHEADS + h) * SEQ + s) << 6));
    float4 q0 = qv[0],  q1 = qv[1],  q2 = qv[2],  q3 = qv[3];
    float4 q4 = qv[4],  q5 = qv[5],  q6 = qv[6],  q7 = qv[7];
    float4 q8 = qv[8],  q9 = qv[9],  q10 = qv[10], q11 = qv[11];
    float4 q12 = qv[12], q13 = qv[13], q14 = qv[14], q15 = qv[15];
    float ss = SS(q0)+SS(q1)+SS(q2)+SS(q3)+SS(q4)+SS(q5)+SS(q6)+SS(q7)
             + SS(q8)+SS(q9)+SS(q10)+SS(q11)+SS(q12)+SS(q13)+SS(q14)+SS(q15);
    const float qs = 1.0f / (fmaxf(sqrtf(ss), EPS) * 8.0f);

    float tv[8]; int ti[8];
#pragma unroll
    for (int j = 0; j < 8; ++j) { tv[j] = -1e30f; ti[j] = 0x7fffffff; }

    const int* cp = pcand + (((size_t)h * NQ + n) * 8 + p) * 16;
    const float* kb = kmem + ((size_t)h << 20);   // h*16384*64
    const float* nb = knr + h * MMEM;

#pragma unroll 1
    for (int c = 0; c < 16; ++c) {
        const int idx = cp[c];
        const float4* kp = (const float4*)(kb + ((size_t)idx << 6));
        float a0 = 0.f, a1 = 0.f, a2 = 0.f, a3 = 0.f;
        float4 kv;
        KROW(0, q0)  KROW(1, q1)  KROW(2, q2)  KROW(3, q3)
        KROW(4, q4)  KROW(5, q5)  KROW(6, q6)  KROW(7, q7)
        KROW(8, q8)  KROW(9, q9)  KROW(10, q10) KROW(11, q11)
        KROW(12, q12) KROW(13, q13) KROW(14, q14) KROW(15, q15)
        const float sc = ((a0 + a1) + (a2 + a3)) * qs * nb[idx];
        if (sc > tv[7] || (sc == tv[7] && idx < ti[7])) {
            tv[7] = sc; ti[7] = idx;
#pragma unroll
            for (int j = 7; j > 0; --j) {
                bool sw = (tv[j] > tv[j-1]) || (tv[j] == tv[j-1] && ti[j] < ti[j-1]);
                if (sw) {
                    float tf = tv[j]; tv[j] = tv[j-1]; tv[j-1] = tf;
                    int   tu = ti[j]; ti[j] = ti[j-1]; ti[j-1] = tu;
                }
            }
        }
    }

    const size_t ob = (((size_t)h * NQ + n) * 8 + p) * 8;
#pragma unroll
    for (int j = 0; j < 8; ++j) { pscore[ob + j] = tv[j]; pidx[ob + j] = ti[j]; }
}

// ---------------------------------------------------------------------------
// Kernel 5: merge P partial top-8 lists (fp32-exact, tie-safe since each list
// is (score desc, idx asc) and partitions ascend in index), gather values,
// sigmoid-gate blend.
// ---------------------------------------------------------------------------
__global__ void merge_kernel(const float* __restrict__ pscore,
                             const int* __restrict__ pidx,
                             const float* __restrict__ vmem,
                             const float* __restrict__ outputs,
                             const float* __restrict__ gate,
                             float* __restrict__ out, int P) {
    const int t = blockIdx.x * 256 + threadIdx.x;
    const int h = t >> 10;
    const int n = t & 1023;
    const int b = n >> 9;
    const int s = n & 511;

    float tv[8]; int ti[8];
    const size_t base = ((size_t)h * NQ + n) * P * 8;
#pragma unroll
    for (int j = 0; j < 8; ++j) { tv[j] = pscore[base + j]; ti[j] = pidx[base + j]; }
    const int total = P * 8;
    for (int c = 8; c < total; ++c) {
        const float v = pscore[base + c];
        if (v > tv[7]) {
            tv[7] = v; ti[7] = pidx[base + c];
#pragma unroll
            for (int j = 7; j > 0; --j) {
                if (tv[j] > tv[j-1]) {
                    float tf = tv[j]; tv[j] = tv[j-1]; tv[j-1] = tf;
                    int   tu = ti[j]; ti[j] = ti[j-1]; ti[j-1] = tu;
                }
            }
        }
    }

    float4 acc[16];
#pragma unroll
    for (int i = 0; i < 16; ++i) acc[i] = make_float4(0.f, 0.f, 0.f, 0.f);
#pragma unroll
    for (int j = 0; j < 8; ++j) {
        const float4* vp = reinterpret_cast<const float4*>(
            vmem + ((size_t)h * MMEM + ti[j]) * HD);
        const float sc = tv[j];
#pragma unroll
        for (int i = 0; i < 16; ++i) {
            float4 v = vp[i];
            acc[i].x = fmaf(sc, v.x, acc[i].x);
            acc[i].y = fmaf(sc, v.y, acc[i].y);
            acc[i].z = fmaf(sc, v.z, acc[i].z);
            acc[i].w = fmaf(sc, v.w, acc[i].w);
        }
    }

    const float g  = 1.0f / (1.0f + expf(-gate[h]));
    const float og = 1.0f - g;
    const size_t off = (((size_t)b * NHEADS + h) * SEQ + s) * HD;
    const float4* op = reinterpret_cast<const float4*>(outputs + off);
    float4* dst = reinterpret_cast<float4*>(out + off);
#pragma unroll
    for (int i = 0; i < 16; ++i) {
        float4 o = op[i];
        float4 r;
        r.x = g * acc[i].x + og * o.x;
        r.y = g * acc[i].y + og * o.y;
        r.z = g * acc[i].z + og * o.z;
        r.w = g * acc[i].w + og * o.w;
        dst[i] = r;
    }
}

// ---------------------------------------------------------------------------
// Fallback fp32 scan (previous round's kernel), used only if ws is too small.
// ---------------------------------------------------------------------------
__global__ __launch_bounds__(64, 4)
void scan_kernel(const float* __restrict__ query,
                 const float* __restrict__ kmem,
                 const float* __restrict__ knr,
                 float* __restrict__ pscore,
                 int* __restrict__ pidx,
                 int P, int CH) {
    const int lane = threadIdx.x & 63;
    int bid = blockIdx.x;
    const int p  = bid % P;  bid /= P;
    const int qb = bid & 15; bid >>= 4;
    const int h  = bid;
    const int n  = qb * 64 + lane;
    const int b  = n >> 9;
    const int s  = n & 511;

    const float4* qp = reinterpret_cast<const float4*>(
        query + (((size_t)b * NHEADS + h) * SEQ + s) * HD);
    float q[HD];
    float ss = 0.0f;
#pragma unroll
    for (int i = 0; i < 16; ++i) {
        float4 v = qp[i];
        q[4*i+0] = v.x; q[4*i+1] = v.y; q[4*i+2] = v.z; q[4*i+3] = v.w;
        ss += v.x * v.x + v.y * v.y + v.z * v.z + v.w * v.w;
    }
    const float rq = 1.0f / (fmaxf(sqrtf(ss), EPS) * 8.0f);
#pragma unroll
    for (int i = 0; i < HD; ++i) q[i] *= rq;

    float tv[8]; int ti[8];
#pragma unroll
    for (int j = 0; j < 8; ++j) { tv[j] = -INFINITY; ti[j] = 0; }

    const int m0 = p * CH;
    const float4* kp = reinterpret_cast<const float4*>(
        kmem + ((size_t)h * MMEM + m0) * HD);
    const float* knrp = knr + h * MMEM + m0;

    for (int mm = 0; mm < CH; ++mm) {
        float d0 = 0.f, d1 = 0.f, d2 = 0.f, d3 = 0.f;
#pragma unroll
        for (int i = 0; i < 16; ++i) {
            float4 kv = kp[(size_t)mm * 16 + i];
            d0 = fmaf(q[4*i+0], kv.x, d0);
            d1 = fmaf(q[4*i+1], kv.y, d1);
            d2 = fmaf(q[4*i+2], kv.z, d2);
            d3 = fmaf(q[4*i+3], kv.w, d3);
        }
        const float sim = ((d0 + d1) + (d2 + d3)) * knrp[mm];
        if (sim > tv[7]) {
            tv[7] = sim; ti[7] = m0 + mm;
#pragma unroll
            for (int j = 7; j > 0; --j) {
                if (tv[j] > tv[j-1]) {
                    float tf = tv[j]; tv[j] = tv[j-1]; tv[j-1] = tf;
                    int   tu = ti[j]; ti[j] = ti[j-1]; ti[j-1] = tu;
                }
            }
        }
    }

    const size_t base = (((size_t)h * NQ + n) * P + p) * 8;
#pragma unroll
    for (int j = 0; j < 8; ++j) { pscore[base+j] = tv[j]; pidx[base+j] = ti[j]; }
}

// ---------------------------------------------------------------------------
extern "C" void kernel_launch(void* const* d_in, const int* in_sizes, int n_in,
                              void* d_out, int out_size, void* d_ws, size_t ws_size,
                              hipStream_t stream) {
    const float* query   = (const float*)d_in[1];
    const float* outputs = (const float*)d_in[4];
    const float* gate    = (const float*)d_in[5];
    const float* kmem    = (const float*)d_in[6];
    const float* vmem    = (const float*)d_in[7];
    float* out = (float*)d_out;

    const size_t sz_knr   = (size_t)NHEADS * MMEM * 4;               //  1.0 MB
    const size_t sz_kbf   = (size_t)NHEADS * MMEM * HD * 2;          // 33.5 MB
    const size_t sz_pcand = (size_t)NHEADS * NQ * 8 * 16 * 4;        //  8.4 MB
    const size_t sz_plist = (size_t)NHEADS * NQ * 8 * 8 * 4;         //  4.2 MB
    const size_t need = sz_knr + sz_kbf + sz_pcand + 2 * sz_plist;

    if (ws_size >= need) {
        char* w = (char*)d_ws;
        float*          knr     = (float*)w;                 w += sz_knr;
        unsigned short* kbf     = (unsigned short*)w;        w += sz_kbf;
        int*            pcand   = (int*)w;                   w += sz_pcand;
        float*          pscore2 = (float*)w;                 w += sz_plist;
        int*            pidx2   = (int*)w;

        knorm_kernel<<<(NHEADS * MMEM * 16) / 256, 256, 0, stream>>>(kmem, knr);
        kprep_kernel<<<(NHEADS * 512 * 4 * 64) / 256, 256, 0, stream>>>(kmem, knr, kbf);
        scan_mfma_kernel<<<NHEADS * 4 * 8, 256, 0, stream>>>(query, kbf, pcand);
        rescore_kernel<<<(NHEADS * NQ * 8) / 256, 256, 0, stream>>>(
            query, kmem, knr, pcand, pscore2, pidx2);
        merge_kernel<<<(NHEADS * NQ) / 256, 256, 0, stream>>>(
            pscore2, pidx2, vmem, outputs, gate, out, 8);
    } else {
        int P = 16;
        while (P > 4 &&
               (size_t)NHEADS * MMEM * 4 + (size_t)NHEADS * NQ * (size_t)P * 64 > ws_size)
            P >>= 1;
        const int CH = MMEM / P;

        float* knr    = (float*)d_ws;
        float* pscore = knr + (size_t)NHEADS * MMEM;
        int*   pidx   = (int*)(pscore + (size_t)NHEADS * NQ * (size_t)P * 8);

        knorm_kernel<<<(NHEADS * MMEM * 16) / 256, 256, 0, stream>>>(kmem, knr);
        scan_kernel<<<NHEADS * 16 * P, 64, 0, stream>>>(
            query, kmem, knr, pscore, pidx, P, CH);
        merge_kernel<<<(NHEADS * NQ) / 256, 256, 0, stream>>>(
            pscore, pidx, vmem, outputs, gate, out, P);
    }
}

// Round 5
// 694.415 us; speedup vs baseline: 1.9258x; 1.2275x over previous
//
#include <hip/hip_runtime.h>
#include <math.h>

#define NHEADS 16
#define HD 64
#define MMEM 16384
#define NQ 1024   // B*S per head
#define SEQ 512
#define EPS 1e-8f
#define NPART 8
#define NT 64     // tiles (32 mems each) per partition: 16384/(8*32)

typedef short bf16x8 __attribute__((ext_vector_type(8)));
typedef float f32x16 __attribute__((ext_vector_type(16)));

__device__ inline unsigned short f2bf(float f) {
    unsigned int u = __builtin_bit_cast(unsigned int, f);
    unsigned int r = (u + 0x7FFFu + ((u >> 16) & 1u)) >> 16;  // RNE
    return (unsigned short)r;
}

// ---------------------------------------------------------------------------
// Kernel 1: reciprocal L2 norm per key-memory row.
// ---------------------------------------------------------------------------
__global__ void knorm_kernel(const float* __restrict__ kmem,
                             float* __restrict__ knr) {
    int gid = blockIdx.x * 256 + threadIdx.x;
    int mem = gid >> 4;
    int d4  = gid & 15;
    float4 kv = reinterpret_cast<const float4*>(kmem)[(size_t)mem * 16 + d4];
    float ss = kv.x * kv.x + kv.y * kv.y + kv.z * kv.z + kv.w * kv.w;
    ss += __shfl_xor(ss, 1);
    ss += __shfl_xor(ss, 2);
    ss += __shfl_xor(ss, 4);
    ss += __shfl_xor(ss, 8);
    if (d4 == 0) knr[mem] = 1.0f / fmaxf(sqrtf(ss), EPS);
}

// ---------------------------------------------------------------------------
// Kernel 2: normalized bf16 keys in MFMA-A-fragment tile order.
// Tile = 32 mems x 64 d. Byte layout: (((h*512+t)*4+ks)*64+lane)*16 + j*2
// holds kmem[h][t*32+(lane&31)][ks*16+(lane>>5)*8+j] * knr (bf16).
// ---------------------------------------------------------------------------
__global__ __launch_bounds__(256)
void kprep_kernel(const float* __restrict__ kmem,
                  const float* __restrict__ knr,
                  unsigned short* __restrict__ kbf) {
    int gid = blockIdx.x * 256 + threadIdx.x;
    int lane = gid & 63;
    int ks   = (gid >> 6) & 3;
    int t    = (gid >> 8) & 511;
    int h    = gid >> 17;
    int row  = t * 32 + (lane & 31);
    int d0   = ks * 16 + ((lane >> 5) << 3);
    const float* src = kmem + (((size_t)h * MMEM + row) << 6) + d0;
    float sc = knr[h * MMEM + row];
    float4 v0 = *(const float4*)(src);
    float4 v1 = *(const float4*)(src + 4);
    uint4 o;
    o.x = (unsigned)f2bf(v0.x * sc) | ((unsigned)f2bf(v0.y * sc) << 16);
    o.y = (unsigned)f2bf(v0.z * sc) | ((unsigned)f2bf(v0.w * sc) << 16);
    o.z = (unsigned)f2bf(v1.x * sc) | ((unsigned)f2bf(v1.y * sc) << 16);
    o.w = (unsigned)f2bf(v1.z * sc) | ((unsigned)f2bf(v1.w * sc) << 16);
    *(uint4*)(kbf + (size_t)gid * 8) = o;
}

// ---------------------------------------------------------------------------
// Kernel 3: barrier-free MFMA candidate scan. One wave per block.
// Wave: 32 queries (one MFMA col-group) x 2048-mem partition (64 tiles).
// K-fragments ping-pong straight through registers (global_load_dwordx4);
// no LDS, no __syncthreads. D-layout: col=lane&31 (query),
// row=(reg&3)+8*(reg>>2)+4*(lane>>5) (mem). Per-lane running top-8 over its
// 16-row half; 2 lanes/query -> 16 candidates per (query, partition).
// ---------------------------------------------------------------------------
#define EPILOG(ACC, TV, TI, MB) do {                                          \
    float _m = fmaxf(fmaxf(fmaxf(ACC[0],ACC[1]),fmaxf(ACC[2],ACC[3])),        \
                     fmaxf(fmaxf(ACC[4],ACC[5]),fmaxf(ACC[6],ACC[7])));       \
    _m = fmaxf(_m, fmaxf(fmaxf(fmaxf(ACC[8],ACC[9]),fmaxf(ACC[10],ACC[11])), \
                         fmaxf(fmaxf(ACC[12],ACC[13]),fmaxf(ACC[14],ACC[15]))));\
    if (_m > TV[7]) {                                                         \
        _Pragma("unroll")                                                     \
        for (int _r = 0; _r < 16; ++_r) {                                     \
            float _v = ACC[_r];                                               \
            if (_v > TV[7]) {                                                 \
                TV[7] = _v; TI[7] = (MB) + (_r & 3) + 8 * (_r >> 2);          \
                _Pragma("unroll")                                             \
                for (int _j = 7; _j > 0; --_j) {                              \
                    if (TV[_j] > TV[_j-1]) {                                  \
                        float _tf = TV[_j]; TV[_j] = TV[_j-1]; TV[_j-1] = _tf;\
                        int _tu = TI[_j]; TI[_j] = TI[_j-1]; TI[_j-1] = _tu;  \
                    } } } } }                                                 \
} while (0)

__device__ inline bf16x8 pack8(const float* p) {
    float4 a = *(const float4*)p;
    float4 b = *(const float4*)(p + 4);
    bf16x8 f;
    f[0] = (short)f2bf(a.x); f[1] = (short)f2bf(a.y);
    f[2] = (short)f2bf(a.z); f[3] = (short)f2bf(a.w);
    f[4] = (short)f2bf(b.x); f[5] = (short)f2bf(b.y);
    f[6] = (short)f2bf(b.z); f[7] = (short)f2bf(b.w);
    return f;
}

__global__ __launch_bounds__(64, 4)
void scan_mfma_kernel(const float* __restrict__ query,
                      const unsigned short* __restrict__ kbf,
                      int* __restrict__ pcand) {
    const int lane = threadIdx.x;
    int bid = blockIdx.x;
    const int p  = bid & 7;  bid >>= 3;
    const int qg = bid & 31; bid >>= 5;
    const int h  = bid;

    const int col = lane & 31;
    const int hi  = lane >> 5;
    const int n   = qg * 32 + col;

    // B fragments (raw queries; per-query scale doesn't change that query's ranking)
    bf16x8 qf0, qf1, qf2, qf3;
    {
        const int b0 = n >> 9, s0 = n & 511;
        const float* qp = query + ((((size_t)b0 * NHEADS + h) * SEQ + s0) << 6);
        qf0 = pack8(qp + 0  + hi * 8);
        qf1 = pack8(qp + 16 + hi * 8);
        qf2 = pack8(qp + 32 + hi * 8);
        qf3 = pack8(qp + 48 + hi * 8);
    }

    float tv[8]; int ti[8];
#pragma unroll
    for (int j = 0; j < 8; ++j) { tv[j] = -1e30f; ti[j] = 0; }

    const unsigned char* ptr = (const unsigned char*)kbf
        + ((size_t)h * 512 + (size_t)p * NT) * 4096 + (size_t)lane * 16;
    const int mbase0 = p * (NT * 32) + 4 * hi;

    bf16x8 aA0, aA1, aA2, aA3, aB0, aB1, aB2, aB3;
    aA0 = *(const bf16x8*)(ptr + 0);
    aA1 = *(const bf16x8*)(ptr + 1024);
    aA2 = *(const bf16x8*)(ptr + 2048);
    aA3 = *(const bf16x8*)(ptr + 3072);

#pragma unroll 1
    for (int t = 0; t < NT; t += 2) {
        // prefetch tile t+1 into B regs
        {
            const unsigned char* pn = ptr + (size_t)(t + 1) * 4096;
            aB0 = *(const bf16x8*)(pn + 0);
            aB1 = *(const bf16x8*)(pn + 1024);
            aB2 = *(const bf16x8*)(pn + 2048);
            aB3 = *(const bf16x8*)(pn + 3072);
        }
        f32x16 acc = {0,0,0,0,0,0,0,0,0,0,0,0,0,0,0,0};
        acc = __builtin_amdgcn_mfma_f32_32x32x16_bf16(aA0, qf0, acc, 0, 0, 0);
        acc = __builtin_amdgcn_mfma_f32_32x32x16_bf16(aA1, qf1, acc, 0, 0, 0);
        acc = __builtin_amdgcn_mfma_f32_32x32x16_bf16(aA2, qf2, acc, 0, 0, 0);
        acc = __builtin_amdgcn_mfma_f32_32x32x16_bf16(aA3, qf3, acc, 0, 0, 0);
        EPILOG(acc, tv, ti, mbase0 + t * 32);

        // prefetch tile t+2 into A regs
        if (t + 2 < NT) {
            const unsigned char* p2 = ptr + (size_t)(t + 2) * 4096;
            aA0 = *(const bf16x8*)(p2 + 0);
            aA1 = *(const bf16x8*)(p2 + 1024);
            aA2 = *(const bf16x8*)(p2 + 2048);
            aA3 = *(const bf16x8*)(p2 + 3072);
        }
        f32x16 acc2 = {0,0,0,0,0,0,0,0,0,0,0,0,0,0,0,0};
        acc2 = __builtin_amdgcn_mfma_f32_32x32x16_bf16(aB0, qf0, acc2, 0, 0, 0);
        acc2 = __builtin_amdgcn_mfma_f32_32x32x16_bf16(aB1, qf1, acc2, 0, 0, 0);
        acc2 = __builtin_amdgcn_mfma_f32_32x32x16_bf16(aB2, qf2, acc2, 0, 0, 0);
        acc2 = __builtin_amdgcn_mfma_f32_32x32x16_bf16(aB3, qf3, acc2, 0, 0, 0);
        EPILOG(acc2, tv, ti, mbase0 + (t + 1) * 32);
    }

    const size_t base = (((size_t)h * NQ + n) * NPART + p) * 16 + hi * 8;
#pragma unroll
    for (int j = 0; j < 8; ++j) pcand[base + j] = ti[j];
}

// ---------------------------------------------------------------------------
// Kernel 4: exact fp32 rescore of 16 candidates per (query, partition);
// per-partition top-8 with (score desc, idx asc) tie rule.
// ---------------------------------------------------------------------------
#define KROW(I, Q) kv = kp[I]; \
    a0 = fmaf(Q.x, kv.x, a0); a1 = fmaf(Q.y, kv.y, a1); \
    a2 = fmaf(Q.z, kv.z, a2); a3 = fmaf(Q.w, kv.w, a3);
#define SS(Q) (Q.x*Q.x + Q.y*Q.y + Q.z*Q.z + Q.w*Q.w)

__global__ __launch_bounds__(256, 4)
void rescore_kernel(const float* __restrict__ query,
                    const float* __restrict__ kmem,
                    const float* __restrict__ knr,
                    const int* __restrict__ pcand,
                    float* __restrict__ pscore,
                    int* __restrict__ pidx) {
    int gid = blockIdx.x * 256 + threadIdx.x;  // (h, q, p)
    int p = gid & 7;
    int n = (gid >> 3) & 1023;
    int h = gid >> 13;
    int b = n >> 9, s = n & 511;
    const float4* qv = (const float4*)(query + ((((size_t)b * NHEADS + h) * SEQ + s) << 6));
    float4 q0 = qv[0],  q1 = qv[1],  q2 = qv[2],  q3 = qv[3];
    float4 q4 = qv[4],  q5 = qv[5],  q6 = qv[6],  q7 = qv[7];
    float4 q8 = qv[8],  q9 = qv[9],  q10 = qv[10], q11 = qv[11];
    float4 q12 = qv[12], q13 = qv[13], q14 = qv[14], q15 = qv[15];
    float ss = SS(q0)+SS(q1)+SS(q2)+SS(q3)+SS(q4)+SS(q5)+SS(q6)+SS(q7)
             + SS(q8)+SS(q9)+SS(q10)+SS(q11)+SS(q12)+SS(q13)+SS(q14)+SS(q15);
    const float qs = 1.0f / (fmaxf(sqrtf(ss), EPS) * 8.0f);

    float tv[8]; int ti[8];
#pragma unroll
    for (int j = 0; j < 8; ++j) { tv[j] = -1e30f; ti[j] = 0x7fffffff; }

    const int* cp = pcand + (((size_t)h * NQ + n) * NPART + p) * 16;
    const float* kb = kmem + ((size_t)h << 20);   // h*16384*64
    const float* nb = knr + h * MMEM;

#pragma unroll 1
    for (int c = 0; c < 16; ++c) {
        const int idx = cp[c];
        const float4* kp = (const float4*)(kb + ((size_t)idx << 6));
        float a0 = 0.f, a1 = 0.f, a2 = 0.f, a3 = 0.f;
        float4 kv;
        KROW(0, q0)  KROW(1, q1)  KROW(2, q2)  KROW(3, q3)
        KROW(4, q4)  KROW(5, q5)  KROW(6, q6)  KROW(7, q7)
        KROW(8, q8)  KROW(9, q9)  KROW(10, q10) KROW(11, q11)
        KROW(12, q12) KROW(13, q13) KROW(14, q14) KROW(15, q15)
        const float sc = ((a0 + a1) + (a2 + a3)) * qs * nb[idx];
        if (sc > tv[7] || (sc == tv[7] && idx < ti[7])) {
            tv[7] = sc; ti[7] = idx;
#pragma unroll
            for (int j = 7; j > 0; --j) {
                bool sw = (tv[j] > tv[j-1]) || (tv[j] == tv[j-1] && ti[j] < ti[j-1]);
                if (sw) {
                    float tf = tv[j]; tv[j] = tv[j-1]; tv[j-1] = tf;
                    int   tu = ti[j]; ti[j] = ti[j-1]; ti[j-1] = tu;
                }
            }
        }
    }

    const size_t ob = (((size_t)h * NQ + n) * NPART + p) * 8;
#pragma unroll
    for (int j = 0; j < 8; ++j) { pscore[ob + j] = tv[j]; pidx[ob + j] = ti[j]; }
}

// ---------------------------------------------------------------------------
// Kernel 5: merge P partial top-8 lists (fp32-exact, tie-safe since each list
// is (score desc, idx asc) and partitions ascend in index), gather values,
// sigmoid-gate blend.
// ---------------------------------------------------------------------------
__global__ void merge_kernel(const float* __restrict__ pscore,
                             const int* __restrict__ pidx,
                             const float* __restrict__ vmem,
                             const float* __restrict__ outputs,
                             const float* __restrict__ gate,
                             float* __restrict__ out, int P) {
    const int t = blockIdx.x * 256 + threadIdx.x;
    const int h = t >> 10;
    const int n = t & 1023;
    const int b = n >> 9;
    const int s = n & 511;

    float tv[8]; int ti[8];
    const size_t base = ((size_t)h * NQ + n) * P * 8;
#pragma unroll
    for (int j = 0; j < 8; ++j) { tv[j] = pscore[base + j]; ti[j] = pidx[base + j]; }
    const int total = P * 8;
    for (int c = 8; c < total; ++c) {
        const float v = pscore[base + c];
        if (v > tv[7]) {
            tv[7] = v; ti[7] = pidx[base + c];
#pragma unroll
            for (int j = 7; j > 0; --j) {
                if (tv[j] > tv[j-1]) {
                    float tf = tv[j]; tv[j] = tv[j-1]; tv[j-1] = tf;
                    int   tu = ti[j]; ti[j] = ti[j-1]; ti[j-1] = tu;
                }
            }
        }
    }

    float4 acc[16];
#pragma unroll
    for (int i = 0; i < 16; ++i) acc[i] = make_float4(0.f, 0.f, 0.f, 0.f);
#pragma unroll
    for (int j = 0; j < 8; ++j) {
        const float4* vp = reinterpret_cast<const float4*>(
            vmem + ((size_t)h * MMEM + ti[j]) * HD);
        const float sc = tv[j];
#pragma unroll
        for (int i = 0; i < 16; ++i) {
            float4 v = vp[i];
            acc[i].x = fmaf(sc, v.x, acc[i].x);
            acc[i].y = fmaf(sc, v.y, acc[i].y);
            acc[i].z = fmaf(sc, v.z, acc[i].z);
            acc[i].w = fmaf(sc, v.w, acc[i].w);
        }
    }

    const float g  = 1.0f / (1.0f + expf(-gate[h]));
    const float og = 1.0f - g;
    const size_t off = (((size_t)b * NHEADS + h) * SEQ + s) * HD;
    const float4* op = reinterpret_cast<const float4*>(outputs + off);
    float4* dst = reinterpret_cast<float4*>(out + off);
#pragma unroll
    for (int i = 0; i < 16; ++i) {
        float4 o = op[i];
        float4 r;
        r.x = g * acc[i].x + og * o.x;
        r.y = g * acc[i].y + og * o.y;
        r.z = g * acc[i].z + og * o.z;
        r.w = g * acc[i].w + og * o.w;
        dst[i] = r;
    }
}

// ---------------------------------------------------------------------------
// Fallback fp32 scan, used only if ws is too small for the MFMA path.
// ---------------------------------------------------------------------------
__global__ __launch_bounds__(64, 4)
void scan_kernel(const float* __restrict__ query,
                 const float* __restrict__ kmem,
                 const float* __restrict__ knr,
                 float* __restrict__ pscore,
                 int* __restrict__ pidx,
                 int P, int CH) {
    const int lane = threadIdx.x & 63;
    int bid = blockIdx.x;
    const int p  = bid % P;  bid /= P;
    const int qb = bid & 15; bid >>= 4;
    const int h  = bid;
    const int n  = qb * 64 + lane;
    const int b  = n >> 9;
    const int s  = n & 511;

    const float4* qp = reinterpret_cast<const float4*>(
        query + (((size_t)b * NHEADS + h) * SEQ + s) * HD);
    float q[HD];
    float ss = 0.0f;
#pragma unroll
    for (int i = 0; i < 16; ++i) {
        float4 v = qp[i];
        q[4*i+0] = v.x; q[4*i+1] = v.y; q[4*i+2] = v.z; q[4*i+3] = v.w;
        ss += v.x * v.x + v.y * v.y + v.z * v.z + v.w * v.w;
    }
    const float rq = 1.0f / (fmaxf(sqrtf(ss), EPS) * 8.0f);
#pragma unroll
    for (int i = 0; i < HD; ++i) q[i] *= rq;

    float tv[8]; int ti[8];
#pragma unroll
    for (int j = 0; j < 8; ++j) { tv[j] = -INFINITY; ti[j] = 0; }

    const int m0 = p * CH;
    const float4* kp = reinterpret_cast<const float4*>(
        kmem + ((size_t)h * MMEM + m0) * HD);
    const float* knrp = knr + h * MMEM + m0;

    for (int mm = 0; mm < CH; ++mm) {
        float d0 = 0.f, d1 = 0.f, d2 = 0.f, d3 = 0.f;
#pragma unroll
        for (int i = 0; i < 16; ++i) {
            float4 kv = kp[(size_t)mm * 16 + i];
            d0 = fmaf(q[4*i+0], kv.x, d0);
            d1 = fmaf(q[4*i+1], kv.y, d1);
            d2 = fmaf(q[4*i+2], kv.z, d2);
            d3 = fmaf(q[4*i+3], kv.w, d3);
        }
        const float sim = ((d0 + d1) + (d2 + d3)) * knrp[mm];
        if (sim > tv[7]) {
            tv[7] = sim; ti[7] = m0 + mm;
#pragma unroll
            for (int j = 7; j > 0; --j) {
                if (tv[j] > tv[j-1]) {
                    float tf = tv[j]; tv[j] = tv[j-1]; tv[j-1] = tf;
                    int   tu = ti[j]; ti[j] = ti[j-1]; ti[j-1] = tu;
                }
            }
        }
    }

    const size_t base = (((size_t)h * NQ + n) * P + p) * 8;
#pragma unroll
    for (int j = 0; j < 8; ++j) { pscore[base+j] = tv[j]; pidx[base+j] = ti[j]; }
}

// ---------------------------------------------------------------------------
extern "C" void kernel_launch(void* const* d_in, const int* in_sizes, int n_in,
                              void* d_out, int out_size, void* d_ws, size_t ws_size,
                              hipStream_t stream) {
    const float* query   = (const float*)d_in[1];
    const float* outputs = (const float*)d_in[4];
    const float* gate    = (const float*)d_in[5];
    const float* kmem    = (const float*)d_in[6];
    const float* vmem    = (const float*)d_in[7];
    float* out = (float*)d_out;

    const size_t sz_knr   = (size_t)NHEADS * MMEM * 4;               //  1.0 MB
    const size_t sz_kbf   = (size_t)NHEADS * MMEM * HD * 2;          // 33.5 MB
    const size_t sz_pcand = (size_t)NHEADS * NQ * NPART * 16 * 4;    //  8.4 MB
    const size_t sz_plist = (size_t)NHEADS * NQ * NPART * 8 * 4;     //  4.2 MB
    const size_t need = sz_knr + sz_kbf + sz_pcand + 2 * sz_plist;

    if (ws_size >= need) {
        char* w = (char*)d_ws;
        float*          knr     = (float*)w;                 w += sz_knr;
        unsigned short* kbf     = (unsigned short*)w;        w += sz_kbf;
        int*            pcand   = (int*)w;                   w += sz_pcand;
        float*          pscore2 = (float*)w;                 w += sz_plist;
        int*            pidx2   = (int*)w;

        knorm_kernel<<<(NHEADS * MMEM * 16) / 256, 256, 0, stream>>>(kmem, knr);
        kprep_kernel<<<(NHEADS * 512 * 4 * 64) / 256, 256, 0, stream>>>(kmem, knr, kbf);
        scan_mfma_kernel<<<NHEADS * 32 * NPART, 64, 0, stream>>>(query, kbf, pcand);
        rescore_kernel<<<(NHEADS * NQ * NPART) / 256, 256, 0, stream>>>(
            query, kmem, knr, pcand, pscore2, pidx2);
        merge_kernel<<<(NHEADS * NQ) / 256, 256, 0, stream>>>(
            pscore2, pidx2, vmem, outputs, gate, out, NPART);
    } else {
        int P = 16;
        while (P > 4 &&
               (size_t)NHEADS * MMEM * 4 + (size_t)NHEADS * NQ * (size_t)P * 64 > ws_size)
            P >>= 1;
        const int CH = MMEM / P;

        float* knr    = (float*)d_ws;
        float* pscore = knr + (size_t)NHEADS * MMEM;
        int*   pidx   = (int*)(pscore + (size_t)NHEADS * NQ * (size_t)P * 8);

        knorm_kernel<<<(NHEADS * MMEM * 16) / 256, 256, 0, stream>>>(kmem, knr);
        scan_kernel<<<NHEADS * 16 * P, 64, 0, stream>>>(
            query, kmem, knr, pscore, pidx, P, CH);
        merge_kernel<<<(NHEADS * NQ) / 256, 256, 0, stream>>>(
            pscore, pidx, vmem, outputs, gate, out, P);
    }
}

// Round 6
// 348.149 us; speedup vs baseline: 3.8411x; 1.9946x over previous
//
#include <hip/hip_runtime.h>
#include <math.h>

#define NHEADS 16
#define HD 64
#define MMEM 16384
#define NQ 1024   // B*S per head
#define SEQ 512
#define EPS 1e-8f
#define NPART 8
#define NT 64     // tiles (32 mems each) per partition: 16384/(8*32)
#define CMAX 16   // candidate slots per (query, partition, lane-half)

typedef short bf16x8 __attribute__((ext_vector_type(8)));
typedef float f32x16 __attribute__((ext_vector_type(16)));

__device__ inline unsigned short f2bf(float f) {
    unsigned int u = __builtin_bit_cast(unsigned int, f);
    unsigned int r = (u + 0x7FFFu + ((u >> 16) & 1u)) >> 16;  // RNE
    return (unsigned short)r;
}

// ---------------------------------------------------------------------------
// Kernel 1: reciprocal L2 norm per key-memory row.
// ---------------------------------------------------------------------------
__global__ void knorm_kernel(const float* __restrict__ kmem,
                             float* __restrict__ knr) {
    int gid = blockIdx.x * 256 + threadIdx.x;
    int mem = gid >> 4;
    int d4  = gid & 15;
    float4 kv = reinterpret_cast<const float4*>(kmem)[(size_t)mem * 16 + d4];
    float ss = kv.x * kv.x + kv.y * kv.y + kv.z * kv.z + kv.w * kv.w;
    ss += __shfl_xor(ss, 1);
    ss += __shfl_xor(ss, 2);
    ss += __shfl_xor(ss, 4);
    ss += __shfl_xor(ss, 8);
    if (d4 == 0) knr[mem] = 1.0f / fmaxf(sqrtf(ss), EPS);
}

// ---------------------------------------------------------------------------
// Kernel 2: normalized bf16 keys in MFMA-A-fragment tile order.
// Tile = 32 mems x 64 d. Byte layout: (((h*512+t)*4+ks)*64+lane)*16 + j*2
// holds kmem[h][t*32+(lane&31)][ks*16+(lane>>5)*8+j] * knr (bf16).
// ---------------------------------------------------------------------------
__global__ __launch_bounds__(256)
void kprep_kernel(const float* __restrict__ kmem,
                  const float* __restrict__ knr,
                  unsigned short* __restrict__ kbf) {
    int gid = blockIdx.x * 256 + threadIdx.x;
    int lane = gid & 63;
    int ks   = (gid >> 6) & 3;
    int t    = (gid >> 8) & 511;
    int h    = gid >> 17;
    int row  = t * 32 + (lane & 31);
    int d0   = ks * 16 + ((lane >> 5) << 3);
    const float* src = kmem + (((size_t)h * MMEM + row) << 6) + d0;
    float sc = knr[h * MMEM + row];
    float4 v0 = *(const float4*)(src);
    float4 v1 = *(const float4*)(src + 4);
    uint4 o;
    o.x = (unsigned)f2bf(v0.x * sc) | ((unsigned)f2bf(v0.y * sc) << 16);
    o.y = (unsigned)f2bf(v0.z * sc) | ((unsigned)f2bf(v0.w * sc) << 16);
    o.z = (unsigned)f2bf(v1.x * sc) | ((unsigned)f2bf(v1.y * sc) << 16);
    o.w = (unsigned)f2bf(v1.z * sc) | ((unsigned)f2bf(v1.w * sc) << 16);
    *(uint4*)(kbf + (size_t)gid * 8) = o;
}

// ---------------------------------------------------------------------------
// Kernel 3: two-pass threshold MFMA candidate scan. One wave per block.
// Pass 1: per-lane top-8 of per-tile maxes via branchless min/max merge
//         (~31 VALU/tile) -> tau = 8th-largest tile-max.
//         Superset proof: if >=8 tiles had max > v8, >=8 values > v8
//         (contradiction), so tau <= v8 and all true top-8 satisfy v >= tau.
// Pass 2: re-MFMA (L2/L3-hot), skip tile unless max16 >= tau; emit v >= tau
//         candidate indices to per-lane global lists (saturating at CMAX;
//         overflow -> rescore does exact full-partition fallback).
// D-layout: col=lane&31 (query), row=(reg&3)+8*(reg>>2)+4*(lane>>5) (mem).
// ---------------------------------------------------------------------------
#define MAX16(ACC)                                                            \
    fmaxf(fmaxf(fmaxf(fmaxf(ACC[0],ACC[1]),fmaxf(ACC[2],ACC[3])),             \
                fmaxf(fmaxf(ACC[4],ACC[5]),fmaxf(ACC[6],ACC[7]))),            \
          fmaxf(fmaxf(fmaxf(ACC[8],ACC[9]),fmaxf(ACC[10],ACC[11])),           \
                fmaxf(fmaxf(ACC[12],ACC[13]),fmaxf(ACC[14],ACC[15]))))

__device__ inline void ins8(float (&tv)[8], float v) {
#pragma unroll
    for (int j = 0; j < 8; ++j) {
        float h_ = fmaxf(tv[j], v);
        float l_ = fminf(tv[j], v);
        tv[j] = h_;
        v = l_;
    }
}

#define EMIT(ACC, MB) do {                                                    \
    float _m = MAX16(ACC);                                                    \
    if (_m >= tauf) {                                                         \
        _Pragma("unroll")                                                     \
        for (int _r = 0; _r < 16; ++_r) {                                     \
            if (ACC[_r] >= tauf) {                                            \
                if (c < CMAX) myc[c] = (MB) + (_r & 3) + 8 * (_r >> 2);       \
                ++c;                                                          \
            }                                                                 \
        }                                                                     \
    }                                                                         \
} while (0)

__device__ inline bf16x8 pack8(const float* p) {
    float4 a = *(const float4*)p;
    float4 b = *(const float4*)(p + 4);
    bf16x8 f;
    f[0] = (short)f2bf(a.x); f[1] = (short)f2bf(a.y);
    f[2] = (short)f2bf(a.z); f[3] = (short)f2bf(a.w);
    f[4] = (short)f2bf(b.x); f[5] = (short)f2bf(b.y);
    f[6] = (short)f2bf(b.z); f[7] = (short)f2bf(b.w);
    return f;
}

__global__ __launch_bounds__(64, 4)
void scan_mfma_kernel(const float* __restrict__ query,
                      const unsigned short* __restrict__ kbf,
                      int* __restrict__ pcand,
                      unsigned int* __restrict__ pcnt) {
    const int lane = threadIdx.x;
    int bid = blockIdx.x;
    const int p  = bid & 7;  bid >>= 3;
    const int qg = bid & 31; bid >>= 5;
    const int h  = bid;

    const int col = lane & 31;
    const int hi  = lane >> 5;
    const int n   = qg * 32 + col;

    // B fragments (raw queries; per-query scale doesn't change that query's ranking)
    bf16x8 qf0, qf1, qf2, qf3;
    {
        const int b0 = n >> 9, s0 = n & 511;
        const float* qp = query + ((((size_t)b0 * NHEADS + h) * SEQ + s0) << 6);
        qf0 = pack8(qp + 0  + hi * 8);
        qf1 = pack8(qp + 16 + hi * 8);
        qf2 = pack8(qp + 32 + hi * 8);
        qf3 = pack8(qp + 48 + hi * 8);
    }

    const unsigned char* ptr = (const unsigned char*)kbf
        + ((size_t)h * 512 + (size_t)p * NT) * 4096 + (size_t)lane * 16;

    // ---------------- pass 1: tau = 8th-largest per-tile max -----------------
    float tv[8];
#pragma unroll
    for (int j = 0; j < 8; ++j) tv[j] = -1e30f;

    {
        bf16x8 aA0, aA1, aA2, aA3, aB0, aB1, aB2, aB3;
        aA0 = *(const bf16x8*)(ptr + 0);
        aA1 = *(const bf16x8*)(ptr + 1024);
        aA2 = *(const bf16x8*)(ptr + 2048);
        aA3 = *(const bf16x8*)(ptr + 3072);

#pragma unroll 1
        for (int t = 0; t < NT; t += 2) {
            {
                const unsigned char* pn = ptr + (size_t)(t + 1) * 4096;
                aB0 = *(const bf16x8*)(pn + 0);
                aB1 = *(const bf16x8*)(pn + 1024);
                aB2 = *(const bf16x8*)(pn + 2048);
                aB3 = *(const bf16x8*)(pn + 3072);
            }
            f32x16 acc = {0,0,0,0,0,0,0,0,0,0,0,0,0,0,0,0};
            acc = __builtin_amdgcn_mfma_f32_32x32x16_bf16(aA0, qf0, acc, 0, 0, 0);
            acc = __builtin_amdgcn_mfma_f32_32x32x16_bf16(aA1, qf1, acc, 0, 0, 0);
            acc = __builtin_amdgcn_mfma_f32_32x32x16_bf16(aA2, qf2, acc, 0, 0, 0);
            acc = __builtin_amdgcn_mfma_f32_32x32x16_bf16(aA3, qf3, acc, 0, 0, 0);
            ins8(tv, MAX16(acc));

            if (t + 2 < NT) {
                const unsigned char* p2 = ptr + (size_t)(t + 2) * 4096;
                aA0 = *(const bf16x8*)(p2 + 0);
                aA1 = *(const bf16x8*)(p2 + 1024);
                aA2 = *(const bf16x8*)(p2 + 2048);
                aA3 = *(const bf16x8*)(p2 + 3072);
            }
            f32x16 acc2 = {0,0,0,0,0,0,0,0,0,0,0,0,0,0,0,0};
            acc2 = __builtin_amdgcn_mfma_f32_32x32x16_bf16(aB0, qf0, acc2, 0, 0, 0);
            acc2 = __builtin_amdgcn_mfma_f32_32x32x16_bf16(aB1, qf1, acc2, 0, 0, 0);
            acc2 = __builtin_amdgcn_mfma_f32_32x32x16_bf16(aB2, qf2, acc2, 0, 0, 0);
            acc2 = __builtin_amdgcn_mfma_f32_32x32x16_bf16(aB3, qf3, acc2, 0, 0, 0);
            ins8(tv, MAX16(acc2));
        }
    }
    const float tauf = tv[7];

    // ---------------- pass 2: emit candidates >= tau -------------------------
    unsigned int c = 0;
    const size_t ch = (((size_t)h * NQ + n) * NPART + p) * 2 + hi;
    int* myc = pcand + ch * CMAX;
    const int mb0 = p * (NT * 32) + 4 * hi;

    {
        bf16x8 aA0, aA1, aA2, aA3, aB0, aB1, aB2, aB3;
        aA0 = *(const bf16x8*)(ptr + 0);
        aA1 = *(const bf16x8*)(ptr + 1024);
        aA2 = *(const bf16x8*)(ptr + 2048);
        aA3 = *(const bf16x8*)(ptr + 3072);

#pragma unroll 1
        for (int t = 0; t < NT; t += 2) {
            {
                const unsigned char* pn = ptr + (size_t)(t + 1) * 4096;
                aB0 = *(const bf16x8*)(pn + 0);
                aB1 = *(const bf16x8*)(pn + 1024);
                aB2 = *(const bf16x8*)(pn + 2048);
                aB3 = *(const bf16x8*)(pn + 3072);
            }
            f32x16 acc = {0,0,0,0,0,0,0,0,0,0,0,0,0,0,0,0};
            acc = __builtin_amdgcn_mfma_f32_32x32x16_bf16(aA0, qf0, acc, 0, 0, 0);
            acc = __builtin_amdgcn_mfma_f32_32x32x16_bf16(aA1, qf1, acc, 0, 0, 0);
            acc = __builtin_amdgcn_mfma_f32_32x32x16_bf16(aA2, qf2, acc, 0, 0, 0);
            acc = __builtin_amdgcn_mfma_f32_32x32x16_bf16(aA3, qf3, acc, 0, 0, 0);
            EMIT(acc, mb0 + t * 32);

            if (t + 2 < NT) {
                const unsigned char* p2 = ptr + (size_t)(t + 2) * 4096;
                aA0 = *(const bf16x8*)(p2 + 0);
                aA1 = *(const bf16x8*)(p2 + 1024);
                aA2 = *(const bf16x8*)(p2 + 2048);
                aA3 = *(const bf16x8*)(p2 + 3072);
            }
            f32x16 acc2 = {0,0,0,0,0,0,0,0,0,0,0,0,0,0,0,0};
            acc2 = __builtin_amdgcn_mfma_f32_32x32x16_bf16(aB0, qf0, acc2, 0, 0, 0);
            acc2 = __builtin_amdgcn_mfma_f32_32x32x16_bf16(aB1, qf1, acc2, 0, 0, 0);
            acc2 = __builtin_amdgcn_mfma_f32_32x32x16_bf16(aB2, qf2, acc2, 0, 0, 0);
            acc2 = __builtin_amdgcn_mfma_f32_32x32x16_bf16(aB3, qf3, acc2, 0, 0, 0);
            EMIT(acc2, mb0 + (t + 1) * 32);
        }
    }
    pcnt[ch] = c;
}

// ---------------------------------------------------------------------------
// Kernel 4: exact fp32 rescore of the candidate lists of both lane-halves;
// per-partition top-8 with (score desc, idx asc) tie rule. If either half
// overflowed CMAX (astronomically rare), do an exact full-partition scan.
// ---------------------------------------------------------------------------
#define KROW(I, Q) kv = kp[I]; \
    a0 = fmaf(Q.x, kv.x, a0); a1 = fmaf(Q.y, kv.y, a1); \
    a2 = fmaf(Q.z, kv.z, a2); a3 = fmaf(Q.w, kv.w, a3);
#define SS(Q) (Q.x*Q.x + Q.y*Q.y + Q.z*Q.z + Q.w*Q.w)
#define DOT64()                                                  \
    float a0 = 0.f, a1 = 0.f, a2 = 0.f, a3 = 0.f;                \
    float4 kv;                                                   \
    KROW(0, q0)  KROW(1, q1)  KROW(2, q2)  KROW(3, q3)           \
    KROW(4, q4)  KROW(5, q5)  KROW(6, q6)  KROW(7, q7)           \
    KROW(8, q8)  KROW(9, q9)  KROW(10, q10) KROW(11, q11)        \
    KROW(12, q12) KROW(13, q13) KROW(14, q14) KROW(15, q15)
#define TINS(SC, IDX)                                                         \
    if ((SC) > tv[7] || ((SC) == tv[7] && (IDX) < ti[7])) {                   \
        tv[7] = (SC); ti[7] = (IDX);                                          \
        _Pragma("unroll")                                                     \
        for (int _j = 7; _j > 0; --_j) {                                      \
            bool _sw = (tv[_j] > tv[_j-1]) ||                                 \
                       (tv[_j] == tv[_j-1] && ti[_j] < ti[_j-1]);             \
            if (_sw) {                                                        \
                float _tf = tv[_j]; tv[_j] = tv[_j-1]; tv[_j-1] = _tf;        \
                int   _tu = ti[_j]; ti[_j] = ti[_j-1]; ti[_j-1] = _tu;        \
            }                                                                 \
        }                                                                     \
    }

__global__ __launch_bounds__(256, 4)
void rescore_kernel(const float* __restrict__ query,
                    const float* __restrict__ kmem,
                    const float* __restrict__ knr,
                    const int* __restrict__ pcand,
                    const unsigned int* __restrict__ pcnt,
                    float* __restrict__ pscore,
                    int* __restrict__ pidx) {
    int gid = blockIdx.x * 256 + threadIdx.x;  // (h, q, p)
    int p = gid & 7;
    int n = (gid >> 3) & 1023;
    int h = gid >> 13;
    int b = n >> 9, s = n & 511;
    const float4* qv = (const float4*)(query + ((((size_t)b * NHEADS + h) * SEQ + s) << 6));
    float4 q0 = qv[0],  q1 = qv[1],  q2 = qv[2],  q3 = qv[3];
    float4 q4 = qv[4],  q5 = qv[5],  q6 = qv[6],  q7 = qv[7];
    float4 q8 = qv[8],  q9 = qv[9],  q10 = qv[10], q11 = qv[11];
    float4 q12 = qv[12], q13 = qv[13], q14 = qv[14], q15 = qv[15];
    float ss = SS(q0)+SS(q1)+SS(q2)+SS(q3)+SS(q4)+SS(q5)+SS(q6)+SS(q7)
             + SS(q8)+SS(q9)+SS(q10)+SS(q11)+SS(q12)+SS(q13)+SS(q14)+SS(q15);
    const float qs = 1.0f / (fmaxf(sqrtf(ss), EPS) * 8.0f);

    float tv[8]; int ti[8];
#pragma unroll
    for (int j = 0; j < 8; ++j) { tv[j] = -1e30f; ti[j] = 0x7fffffff; }

    const size_t ch = (((size_t)h * NQ + n) * NPART + p) * 2;
    const unsigned int c0 = pcnt[ch], c1 = pcnt[ch + 1];
    const float* kb = kmem + ((size_t)h << 20);
    const float* nb = knr + h * MMEM;

    if (c0 > CMAX || c1 > CMAX) {
        // exact fallback: full fp32 scan of the partition (never in practice)
        const int m0 = p * (MMEM / NPART);
#pragma unroll 1
        for (int m = m0; m < m0 + MMEM / NPART; ++m) {
            const float4* kp = (const float4*)(kb + ((size_t)m << 6));
            DOT64()
            const float sc = ((a0 + a1) + (a2 + a3)) * qs * nb[m];
            TINS(sc, m)
        }
    } else {
        const int* l0 = pcand + ch * CMAX;
        const int* l1 = pcand + (ch + 1) * CMAX;
#pragma unroll 1
        for (unsigned int c = 0; c < c0 + c1; ++c) {
            const int idx = (c < c0) ? l0[c] : l1[c - c0];
            const float4* kp = (const float4*)(kb + ((size_t)idx << 6));
            DOT64()
            const float sc = ((a0 + a1) + (a2 + a3)) * qs * nb[idx];
            TINS(sc, idx)
        }
    }

    const size_t ob = (((size_t)h * NQ + n) * NPART + p) * 8;
#pragma unroll
    for (int j = 0; j < 8; ++j) { pscore[ob + j] = tv[j]; pidx[ob + j] = ti[j]; }
}

// ---------------------------------------------------------------------------
// Kernel 5: merge partial top-8 lists (fp32-exact, tie-safe: lists are
// (score desc, idx asc) and partitions ascend in index), gather values,
// sigmoid-gate blend.
// ---------------------------------------------------------------------------
__global__ void merge_kernel(const float* __restrict__ pscore,
                             const int* __restrict__ pidx,
                             const float* __restrict__ vmem,
                             const float* __restrict__ outputs,
                             const float* __restrict__ gate,
                             float* __restrict__ out, int P) {
    const int t = blockIdx.x * 256 + threadIdx.x;
    const int h = t >> 10;
    const int n = t & 1023;
    const int b = n >> 9;
    const int s = n & 511;

    float tv[8]; int ti[8];
    const size_t base = ((size_t)h * NQ + n) * P * 8;
#pragma unroll
    for (int j = 0; j < 8; ++j) { tv[j] = pscore[base + j]; ti[j] = pidx[base + j]; }
    const int total = P * 8;
    for (int c = 8; c < total; ++c) {
        const float v = pscore[base + c];
        if (v > tv[7]) {
            tv[7] = v; ti[7] = pidx[base + c];
#pragma unroll
            for (int j = 7; j > 0; --j) {
                if (tv[j] > tv[j-1]) {
                    float tf = tv[j]; tv[j] = tv[j-1]; tv[j-1] = tf;
                    int   tu = ti[j]; ti[j] = ti[j-1]; ti[j-1] = tu;
                }
            }
        }
    }

    float4 acc[16];
#pragma unroll
    for (int i = 0; i < 16; ++i) acc[i] = make_float4(0.f, 0.f, 0.f, 0.f);
#pragma unroll
    for (int j = 0; j < 8; ++j) {
        const float4* vp = reinterpret_cast<const float4*>(
            vmem + ((size_t)h * MMEM + ti[j]) * HD);
        const float sc = tv[j];
#pragma unroll
        for (int i = 0; i < 16; ++i) {
            float4 v = vp[i];
            acc[i].x = fmaf(sc, v.x, acc[i].x);
            acc[i].y = fmaf(sc, v.y, acc[i].y);
            acc[i].z = fmaf(sc, v.z, acc[i].z);
            acc[i].w = fmaf(sc, v.w, acc[i].w);
        }
    }

    const float g  = 1.0f / (1.0f + expf(-gate[h]));
    const float og = 1.0f - g;
    const size_t off = (((size_t)b * NHEADS + h) * SEQ + s) * HD;
    const float4* op = reinterpret_cast<const float4*>(outputs + off);
    float4* dst = reinterpret_cast<float4*>(out + off);
#pragma unroll
    for (int i = 0; i < 16; ++i) {
        float4 o = op[i];
        float4 r;
        r.x = g * acc[i].x + og * o.x;
        r.y = g * acc[i].y + og * o.y;
        r.z = g * acc[i].z + og * o.z;
        r.w = g * acc[i].w + og * o.w;
        dst[i] = r;
    }
}

// ---------------------------------------------------------------------------
// Fallback fp32 scan, used only if ws is too small for the MFMA path.
// ---------------------------------------------------------------------------
__global__ __launch_bounds__(64, 4)
void scan_kernel(const float* __restrict__ query,
                 const float* __restrict__ kmem,
                 const float* __restrict__ knr,
                 float* __restrict__ pscore,
                 int* __restrict__ pidx,
                 int P, int CH) {
    const int lane = threadIdx.x & 63;
    int bid = blockIdx.x;
    const int p  = bid % P;  bid /= P;
    const int qb = bid & 15; bid >>= 4;
    const int h  = bid;
    const int n  = qb * 64 + lane;
    const int b  = n >> 9;
    const int s  = n & 511;

    const float4* qp = reinterpret_cast<const float4*>(
        query + (((size_t)b * NHEADS + h) * SEQ + s) * HD);
    float q[HD];
    float ss = 0.0f;
#pragma unroll
    for (int i = 0; i < 16; ++i) {
        float4 v = qp[i];
        q[4*i+0] = v.x; q[4*i+1] = v.y; q[4*i+2] = v.z; q[4*i+3] = v.w;
        ss += v.x * v.x + v.y * v.y + v.z * v.z + v.w * v.w;
    }
    const float rq = 1.0f / (fmaxf(sqrtf(ss), EPS) * 8.0f);
#pragma unroll
    for (int i = 0; i < HD; ++i) q[i] *= rq;

    float tv[8]; int ti[8];
#pragma unroll
    for (int j = 0; j < 8; ++j) { tv[j] = -INFINITY; ti[j] = 0; }

    const int m0 = p * CH;
    const float4* kp = reinterpret_cast<const float4*>(
        kmem + ((size_t)h * MMEM + m0) * HD);
    const float* knrp = knr + h * MMEM + m0;

    for (int mm = 0; mm < CH; ++mm) {
        float d0 = 0.f, d1 = 0.f, d2 = 0.f, d3 = 0.f;
#pragma unroll
        for (int i = 0; i < 16; ++i) {
            float4 kv = kp[(size_t)mm * 16 + i];
            d0 = fmaf(q[4*i+0], kv.x, d0);
            d1 = fmaf(q[4*i+1], kv.y, d1);
            d2 = fmaf(q[4*i+2], kv.z, d2);
            d3 = fmaf(q[4*i+3], kv.w, d3);
        }
        const float sim = ((d0 + d1) + (d2 + d3)) * knrp[mm];
        if (sim > tv[7]) {
            tv[7] = sim; ti[7] = m0 + mm;
#pragma unroll
            for (int j = 7; j > 0; --j) {
                if (tv[j] > tv[j-1]) {
                    float tf = tv[j]; tv[j] = tv[j-1]; tv[j-1] = tf;
                    int   tu = ti[j]; ti[j] = ti[j-1]; ti[j-1] = tu;
                }
            }
        }
    }

    const size_t base = (((size_t)h * NQ + n) * P + p) * 8;
#pragma unroll
    for (int j = 0; j < 8; ++j) { pscore[base+j] = tv[j]; pidx[base+j] = ti[j]; }
}

// ---------------------------------------------------------------------------
extern "C" void kernel_launch(void* const* d_in, const int* in_sizes, int n_in,
                              void* d_out, int out_size, void* d_ws, size_t ws_size,
                              hipStream_t stream) {
    const float* query   = (const float*)d_in[1];
    const float* outputs = (const float*)d_in[4];
    const float* gate    = (const float*)d_in[5];
    const float* kmem    = (const float*)d_in[6];
    const float* vmem    = (const float*)d_in[7];
    float* out = (float*)d_out;

    const size_t sz_knr   = (size_t)NHEADS * MMEM * 4;                   //  1.0 MB
    const size_t sz_kbf   = (size_t)NHEADS * MMEM * HD * 2;              // 33.5 MB
    const size_t sz_pcand = (size_t)NHEADS * NQ * NPART * 2 * CMAX * 4;  // 16.8 MB
    const size_t sz_pcnt  = (size_t)NHEADS * NQ * NPART * 2 * 4;         //  1.0 MB
    const size_t sz_plist = (size_t)NHEADS * NQ * NPART * 8 * 4;         //  4.2 MB
    const size_t need = sz_knr + sz_kbf + sz_pcand + sz_pcnt + 2 * sz_plist;

    if (ws_size >= need) {
        char* w = (char*)d_ws;
        float*          knr     = (float*)w;          w += sz_knr;
        unsigned short* kbf     = (unsigned short*)w; w += sz_kbf;
        int*            pcand   = (int*)w;            w += sz_pcand;
        unsigned int*   pcnt    = (unsigned int*)w;   w += sz_pcnt;
        float*          pscore2 = (float*)w;          w += sz_plist;
        int*            pidx2   = (int*)w;

        knorm_kernel<<<(NHEADS * MMEM * 16) / 256, 256, 0, stream>>>(kmem, knr);
        kprep_kernel<<<(NHEADS * 512 * 4 * 64) / 256, 256, 0, stream>>>(kmem, knr, kbf);
        scan_mfma_kernel<<<NHEADS * 32 * NPART, 64, 0, stream>>>(query, kbf, pcand, pcnt);
        rescore_kernel<<<(NHEADS * NQ * NPART) / 256, 256, 0, stream>>>(
            query, kmem, knr, pcand, pcnt, pscore2, pidx2);
        merge_kernel<<<(NHEADS * NQ) / 256, 256, 0, stream>>>(
            pscore2, pidx2, vmem, outputs, gate, out, NPART);
    } else {
        int P = 16;
        while (P > 4 &&
               (size_t)NHEADS * MMEM * 4 + (size_t)NHEADS * NQ * (size_t)P * 64 > ws_size)
            P >>= 1;
        const int CH = MMEM / P;

        float* knr    = (float*)d_ws;
        float* pscore = knr + (size_t)NHEADS * MMEM;
        int*   pidx   = (int*)(pscore + (size_t)NHEADS * NQ * (size_t)P * 8);

        knorm_kernel<<<(NHEADS * MMEM * 16) / 256, 256, 0, stream>>>(kmem, knr);
        scan_kernel<<<NHEADS * 16 * P, 64, 0, stream>>>(
            query, kmem, knr, pscore, pidx, P, CH);
        merge_kernel<<<(NHEADS * NQ) / 256, 256, 0, stream>>>(
            pscore, pidx, vmem, outputs, gate, out, P);
    }
}